// Round 12
// baseline (303.111 us; speedup 1.0000x reference)
//
#include <hip/hip_runtime.h>

#define NPIX 4096
#define CCH  512
#define NGRP 32
#define BATCH 4
#define NT   64

using bf16 = __bf16;
typedef __bf16 bf16x8 __attribute__((ext_vector_type(8)));
typedef __bf16 bf16x4 __attribute__((ext_vector_type(4)));
typedef float  f32x4  __attribute__((ext_vector_type(4)));

__device__ __forceinline__ f32x4 mfma16(bf16x8 a, bf16x8 b, f32x4 c) {
    return __builtin_amdgcn_mfma_f32_16x16x32_bf16(a, b, c, 0, 0, 0);
}

// async global->LDS DMA, 16B per lane. LDS dst = wave-uniform base + lane*16.
__device__ __forceinline__ void gld_lds16(const void* g, void* l) {
    __builtin_amdgcn_global_load_lds(
        (const __attribute__((address_space(1))) unsigned int*)g,
        (__attribute__((address_space(3))) unsigned int*)l,
        16, 0, 0);
}

// ---- swizzle helpers for [16-row][32-col] bf16 units (64B rows, 128B 2-row pairs)
__device__ __forceinline__ void swz_src(int l, int& drow, int& dcol) {
    int m = (l & 7) ^ (l >> 3);
    drow = 2 * (l >> 3) + (m >> 2);
    dcol = (m & 3) * 8;
}
// element offset where global (row c in 0..15, 16B-group g in 0..3) landed
__device__ __forceinline__ int swz_roff(int c, int g) {
    return ((c >> 1) << 6) + ((((((c & 1) << 2) | g)) ^ ((c >> 1) & 7)) << 3);
}

// ---------------- all weights fp32 -> bf16, one launch --------------------------
__global__ __launch_bounds__(256) void cvt_all(const float* __restrict__ wq,
                                               const float* __restrict__ wk,
                                               const float* __restrict__ wv,
                                               const float* __restrict__ wp,
                                               bf16* __restrict__ d, float cscale) {
    int i = blockIdx.x * 256 + threadIdx.x;           // float4 index, 0..262143
    int seg = i >> 16;                                // 65536 float4 per weight
    const float* s = (seg == 0) ? wq : (seg == 1) ? wk : (seg == 2) ? wv : wp;
    float scale = (seg == 0) ? cscale : 1.f;
    float4 v = ((const float4*)s)[i & 65535];
    bf16x4 o;
    o[0] = (bf16)(v.x*scale); o[1] = (bf16)(v.y*scale);
    o[2] = (bf16)(v.z*scale); o[3] = (bf16)(v.w*scale);
    ((bf16x4*)d)[i] = o;
}

// ---------------- groupnorm partial stats: 8 chunks per (b,g), 1024 blocks ------
// (128-block version left half the GPU idle on a 64MB HBM-bound pass)
__global__ __launch_bounds__(256) void gn_part(const float* __restrict__ x,
                                               float2* __restrict__ partials) {
    int blk = blockIdx.x;                             // bg = blk>>3, chunk = blk&7
    const float4* p = (const float4*)(x + (size_t)(blk >> 3) * 65536 + (blk & 7) * 8192);
    float s = 0.f, ss = 0.f;
    int t = threadIdx.x;
    #pragma unroll
    for (int i = 0; i < 8; ++i) {
        float4 v = p[t + i*256];
        s  += v.x + v.y + v.z + v.w;
        ss += v.x*v.x + v.y*v.y + v.z*v.z + v.w*v.w;
    }
    __shared__ float r1[256], r2[256];
    r1[t] = s; r2[t] = ss;
    __syncthreads();
    for (int st = 128; st > 0; st >>= 1) {
        if (t < st) { r1[t] += r1[t+st]; r2[t] += r2[t+st]; }
        __syncthreads();
    }
    if (t == 0) partials[blk] = make_float2(r1[0], r2[0]);
}

// ---------------- groupnorm apply + transpose -> hn_t[b][n][c] bf16 ----------------
// finalizes stats inline from the 8 partials per group (fixed order, deterministic)
__global__ __launch_bounds__(256) void gn_norm_t(const float* __restrict__ x,
                                                 const float2* __restrict__ partials,
                                                 const float* __restrict__ gw,
                                                 const float* __restrict__ gb,
                                                 bf16* __restrict__ hnt) {
    __shared__ float tile[64][65];
    int n0 = blockIdx.x * 64, c0 = blockIdx.y * 64, b = blockIdx.z;
    int t = threadIdx.x;
    {
        int cr = t >> 4;
        int nc = (t & 15) * 4;
        #pragma unroll
        for (int rep = 0; rep < 4; ++rep) {
            int c = c0 + rep*16 + cr;
            int grp = b*NGRP + (c >> 4);              // same for all threads in rep
            float s = 0.f, ss = 0.f;
            #pragma unroll
            for (int k = 0; k < 8; ++k) {
                float2 pp = partials[grp*8 + k];
                s += pp.x; ss += pp.y;
            }
            float mu   = s * (1.f/65536.f);
            float rsig = rsqrtf(ss * (1.f/65536.f) - mu*mu + 1e-6f);
            float w = gw[c], bb = gb[c];
            float4 v = *(const float4*)(x + ((size_t)b*CCH + c)*NPIX + n0 + nc);
            float* dst = &tile[rep*16 + cr][nc];
            dst[0] = (v.x - mu)*rsig*w + bb;
            dst[1] = (v.y - mu)*rsig*w + bb;
            dst[2] = (v.z - mu)*rsig*w + bb;
            dst[3] = (v.w - mu)*rsig*w + bb;
        }
    }
    __syncthreads();
    {
        int nr = t >> 2;
        int cp = (t & 3) * 16;
        bf16x8 o0, o1;
        #pragma unroll
        for (int j = 0; j < 8; ++j) {
            o0[j] = (bf16)tile[cp + j    ][nr];
            o1[j] = (bf16)tile[cp + 8 + j][nr];
        }
        bf16* dst = hnt + ((size_t)b*NPIX + n0 + nr)*CCH + c0 + cp;
        *(bf16x8*)dst       = o0;
        *((bf16x8*)dst + 1) = o1;
    }
}

// ---------------- fused QKV GEMM: one launch over concat [1536x512] weights --------
__global__ __launch_bounds__(256, 2)
void gemm_qkv(const bf16* __restrict__ Wcat, const bf16* __restrict__ X,
              const float* __restrict__ bq, const float* __restrict__ bk,
              const float* __restrict__ bv, bf16* __restrict__ qt,
              bf16* __restrict__ kt, bf16* __restrict__ vch, float cscale) {
    __shared__ bf16 tX[2][4096];   // [128][32] swizzled
    __shared__ bf16 tW[2][4096];
    int n0 = blockIdx.x * 128, o0g = blockIdx.y * 128, b = blockIdx.z;
    int seg = o0g >> 9, osel = o0g & 511;
    const float* bias = (seg == 0) ? bq : (seg == 1) ? bk : bv;
    bf16* Yb = (seg == 0) ? qt : (seg == 1) ? kt : vch;
    float osc = (seg == 0) ? cscale : 1.f;
    bool vmode = (seg == 2);

    int t = threadIdx.x, lane = t & 63, w = t >> 6;
    int wm = (w >> 1) * 64, wn = (w & 1) * 64;
    int col = lane & 15, g = lane >> 4;
    int roff = swz_roff(col, g);
    int drow, dcol;
    swz_src(lane, drow, dcol);
    f32x4 acc[4][4] = {};
    const bf16* gX = X + ((size_t)b*NPIX + n0) * CCH;
    const bf16* gW = Wcat + (size_t)o0g * CCH;

    auto stage = [&](int buf, int k0) {
        #pragma unroll
        for (int i = 0; i < 2; ++i) {
            int rb = (w*2 + i) * 16;
            gld_lds16(gX + (size_t)(rb + drow)*CCH + k0 + dcol, &tX[buf][rb*32]);
            gld_lds16(gW + (size_t)(rb + drow)*CCH + k0 + dcol, &tW[buf][rb*32]);
        }
    };

    stage(0, 0);
    __syncthreads();

    for (int it = 0; it < 16; ++it) {
        int buf = it & 1;
        if (it < 15) stage(buf ^ 1, (it + 1) * 32);
        bf16x8 fA[4], fB[4];
        #pragma unroll
        for (int i = 0; i < 4; ++i) {
            if (!vmode) {
                fA[i] = *(bf16x8*)&tX[buf][(wm + i*16)*32 + roff];
                fB[i] = *(bf16x8*)&tW[buf][(wn + i*16)*32 + roff];
            } else {
                fA[i] = *(bf16x8*)&tW[buf][(wm + i*16)*32 + roff];
                fB[i] = *(bf16x8*)&tX[buf][(wn + i*16)*32 + roff];
            }
        }
        #pragma unroll
        for (int i = 0; i < 4; ++i)
            #pragma unroll
            for (int j = 0; j < 4; ++j)
                acc[i][j] = mfma16(fA[i], fB[j], acc[i][j]);
        __syncthreads();
    }

    int row4 = g * 4;
    #pragma unroll
    for (int i = 0; i < 4; ++i) {
        #pragma unroll
        for (int j = 0; j < 4; ++j) {
            #pragma unroll
            for (int r = 0; r < 4; ++r) {
                float vv = acc[i][j][r];
                int m = wm + i*16 + row4 + r;
                int n = wn + j*16 + col;
                if (!vmode) {
                    int sp = n0 + m, o = osel + n;
                    Yb[((size_t)b*NPIX + sp)*CCH + o] = (bf16)(vv + osc*bias[o]);
                } else {
                    int o = osel + m, sp = n0 + n;
                    Yb[((size_t)b*CCH + o)*NPIX + sp] = (bf16)(vv + bias[o]);
                }
            }
        }
    }
}

// ---------------- proj GEMM: D[o][i] fp32 + bias + residual ------------------------
__global__ __launch_bounds__(256, 2)
void gemm_proj(const bf16* __restrict__ W, const bf16* __restrict__ X,
               const float* __restrict__ bias, float* __restrict__ Yf,
               const float* __restrict__ resid) {
    __shared__ bf16 tX[2][4096];
    __shared__ bf16 tW[2][4096];
    int n0 = blockIdx.x * 128, o0 = blockIdx.y * 128, b = blockIdx.z;
    int t = threadIdx.x, lane = t & 63, w = t >> 6;
    int wm = (w >> 1) * 64, wn = (w & 1) * 64;
    int col = lane & 15, g = lane >> 4;
    int roff = swz_roff(col, g);
    int drow, dcol;
    swz_src(lane, drow, dcol);
    f32x4 acc[4][4] = {};
    const bf16* gX = X + ((size_t)b*NPIX + n0) * CCH;
    const bf16* gW = W + (size_t)o0 * CCH;

    auto stage = [&](int buf, int k0) {
        #pragma unroll
        for (int i = 0; i < 2; ++i) {
            int rb = (w*2 + i) * 16;
            gld_lds16(gX + (size_t)(rb + drow)*CCH + k0 + dcol, &tX[buf][rb*32]);
            gld_lds16(gW + (size_t)(rb + drow)*CCH + k0 + dcol, &tW[buf][rb*32]);
        }
    };

    stage(0, 0);
    __syncthreads();

    for (int it = 0; it < 16; ++it) {
        int buf = it & 1;
        if (it < 15) stage(buf ^ 1, (it + 1) * 32);
        bf16x8 fA[4], fB[4];
        #pragma unroll
        for (int i = 0; i < 4; ++i) {
            fA[i] = *(bf16x8*)&tW[buf][(wm + i*16)*32 + roff];
            fB[i] = *(bf16x8*)&tX[buf][(wn + i*16)*32 + roff];
        }
        #pragma unroll
        for (int i = 0; i < 4; ++i)
            #pragma unroll
            for (int j = 0; j < 4; ++j)
                acc[i][j] = mfma16(fA[i], fB[j], acc[i][j]);
        __syncthreads();
    }

    int row4 = g * 4;
    #pragma unroll
    for (int i = 0; i < 4; ++i) {
        #pragma unroll
        for (int j = 0; j < 4; ++j) {
            #pragma unroll
            for (int r = 0; r < 4; ++r) {
                int o = o0 + wm + i*16 + row4 + r;
                int sp = n0 + wn + j*16 + col;
                size_t idx = ((size_t)b*CCH + o)*NPIX + sp;
                Yf[idx] = acc[i][j][r] + bias[o] + resid[idx];
            }
        }
    }
}

// ---------------- flash attention v9: split staging, no mid-body pin ---------------
// Body t: stage_K(t+1) early; PV(t-1) reads Vt[pb] (wave-private channel blocks) +
// Pl[pb]; lgkmcnt(0) (nearly free -- mfmas consumed the reads); stage_V(t+1) (WAR
// now satisfied by program order); QK^T(t)+exp -> Pl[buf]; one __syncthreads.
// Removes the sched_barrier pin and shortens bv live ranges (spill relief).
__global__ __launch_bounds__(512, 2)
void attn_flash(const bf16* __restrict__ qt, const bf16* __restrict__ kt,
                const bf16* __restrict__ v, bf16* __restrict__ pacc0,
                bf16* __restrict__ pacc1, float* __restrict__ lsum) {
    __shared__ bf16 Kt[2][16384];      // [32 j][512 c], 16B-group XOR swizzle
    __shared__ bf16 Vt[2][16384];      // [512 c][32 j], 16x32-unit swizzle
    __shared__ bf16 Pl[2][8][16][40];  // double-buffered per-wave P tiles
    __shared__ float Ls[128];          // 1/rowsum for all 128 q-rows

    const int L  = blockIdx.x + 32 * blockIdx.y + 128 * blockIdx.z;
    const int gx = L & 7, ix = L >> 3;
    const int b  = gx & 3, jz = gx >> 2;

    const int t = threadIdx.x, lane = t & 63, w = t >> 6;
    const int q0 = ix * 128 + w * 16;          // q-rows owned for QK^T/softmax
    const int col = lane & 15, g = lane >> 4, kq = g * 8;
    const int jbase = jz * 2048;

    const bf16* kbase = kt + (size_t)b*NPIX*CCH;
    const bf16* vbase = v  + (size_t)b*CCH*NPIX;
    int drow, dcol; swz_src(lane, drow, dcol);
    const int kx0 = (col & 7) << 4;
    const int vro = 2*swz_roff(col, g);

    bf16x8 qf[16];
    {
        const bf16* qrow = qt + ((size_t)b*NPIX + q0 + col)*CCH + kq;
        #pragma unroll
        for (int kk = 0; kk < 16; ++kk) qf[kk] = *(const bf16x8*)(qrow + kk*32);
    }

    auto stage_K = [&](int buf, int j0) {
        #pragma unroll
        for (int i = 0; i < 4; ++i) {
            int row = w*4 + i;
            gld_lds16((const char*)(kbase + (size_t)(j0 + row)*CCH) + ((lane*16) ^ ((row & 7) << 4)),
                      (char*)&Kt[buf][0] + row*1024);
        }
    };
    auto stage_V = [&](int buf, int j0) {
        #pragma unroll
        for (int i = 0; i < 4; ++i) {
            int blk = w*4 + i;
            gld_lds16(vbase + (size_t)(blk*16 + drow)*NPIX + j0 + dcol,
                      (char*)&Vt[buf][0] + blk*1024);
        }
    };

    f32x4 acc[8][4] = {};                      // [q-tile][c-tile]; channels w*64..+63
    float lacc[4] = {0.f, 0.f, 0.f, 0.f};

    auto qkt_exp = [&](int buf) {
        f32x4 s0a = {}, s0b = {}, s1a = {}, s1b = {};
        const char* kb0 = (const char*)&Kt[buf][0] + col*1024;
        const char* kb1 = kb0 + 16*1024;
        #pragma unroll
        for (int kk = 0; kk < 16; kk += 2) {
            int e0 = (kk*64     + g*16) ^ kx0;
            int e1 = ((kk+1)*64 + g*16) ^ kx0;
            s0a = mfma16(qf[kk],   *(const bf16x8*)(kb0 + e0), s0a);
            s1a = mfma16(qf[kk],   *(const bf16x8*)(kb1 + e0), s1a);
            s0b = mfma16(qf[kk+1], *(const bf16x8*)(kb0 + e1), s0b);
            s1b = mfma16(qf[kk+1], *(const bf16x8*)(kb1 + e1), s1b);
        }
        f32x4 s0 = s0a + s0b;
        f32x4 s1 = s1a + s1b;
        #pragma unroll
        for (int r = 0; r < 4; ++r) {
            float p0 = __expf(s0[r]);
            float p1 = __expf(s1[r]);
            lacc[r] += p0 + p1;
            Pl[buf][w][g*4 + r][col]      = (bf16)p0;
            Pl[buf][w][g*4 + r][col + 16] = (bf16)p1;
        }
    };

    auto pv = [&](int pb) {                    // PV over Vt[pb], Pl[pb]
        const char* vb = (const char*)&Vt[pb][0] + (w << 12);
        bf16x8 bv0 = *(const bf16x8*)(vb          + vro);
        bf16x8 bv1 = *(const bf16x8*)(vb + 1024   + vro);
        bf16x8 bv2 = *(const bf16x8*)(vb + 2048   + vro);
        bf16x8 bv3 = *(const bf16x8*)(vb + 3072   + vro);
        #pragma unroll
        for (int qtl = 0; qtl < 8; ++qtl) {
            bf16x8 pa = *(bf16x8*)&Pl[pb][qtl][col][kq];
            acc[qtl][0] = mfma16(pa, bv0, acc[qtl][0]);
            acc[qtl][1] = mfma16(pa, bv1, acc[qtl][1]);
            acc[qtl][2] = mfma16(pa, bv2, acc[qtl][2]);
            acc[qtl][3] = mfma16(pa, bv3, acc[qtl][3]);
        }
    };

    stage_K(0, jbase);
    stage_V(0, jbase);
    __syncthreads();

    // peeled body 0: no PV yet
    stage_K(1, jbase + 32);
    stage_V(1, jbase + 32);
    qkt_exp(0);
    __syncthreads();

    for (int it = 1; it < NT; ++it) {
        const int buf = it & 1, pb = buf ^ 1;

        if (it < NT-1) stage_K(pb, jbase + (it + 1) * 32);  // K DMA early

        pv(pb);                                // reads Vt[pb] (own blocks) + Pl[pb]

        // own V/P reads consumed; now safe to overwrite own Vt[pb] blocks
        asm volatile("s_waitcnt lgkmcnt(0)" ::: "memory");
        if (it < NT-1) stage_V(pb, jbase + (it + 1) * 32);

        qkt_exp(buf);
        __syncthreads();
    }

    // tail: PV(NT-1), buffers parity 1
    pv(1);

    // row sums for own 16 q-rows -> Ls + global lsum
    #pragma unroll
    for (int r = 0; r < 4; ++r) {
        float s = lacc[r];
        #pragma unroll
        for (int off = 1; off < 16; off <<= 1) s += __shfl_xor(s, off);
        if (col == 0) {
            Ls[w*16 + g*4 + r] = 1.f / s;
            lsum[((size_t)jz*BATCH + b)*NPIX + q0 + g*4 + r] = s;
        }
    }
    __syncthreads();

    // write partials: channels [w*64, w*64+64), all 128 q-rows
    bf16* pout = jz ? pacc1 : pacc0;
    const int q0b = ix * 128;
    #pragma unroll
    for (int qtl = 0; qtl < 8; ++qtl) {
        f32x4 rlq = *(const f32x4*)&Ls[qtl*16 + g*4];
        #pragma unroll
        for (int i = 0; i < 4; ++i) {
            int ch = w*64 + i*16 + col;
            bf16x4 ov;
            #pragma unroll
            for (int r = 0; r < 4; ++r) ov[r] = (bf16)(acc[qtl][i][r] * rlq[r]);
            *(bf16x4*)(pout + ((size_t)b*CCH + ch)*NPIX + q0b + qtl*16 + g*4) = ov;
        }
    }
}

// ---------------- merge j-split partials + transpose -> h2t[b][n][c] bf16 -----------
__global__ __launch_bounds__(256)
void merge_t(const bf16* __restrict__ p0, const bf16* __restrict__ p1,
             const float* __restrict__ lsum, bf16* __restrict__ h2t) {
    __shared__ float tile[64][65];
    __shared__ float w0s[64], w1s[64];
    int n0 = blockIdx.x * 64, c0 = blockIdx.y * 64, b = blockIdx.z;
    int t = threadIdx.x;
    if (t < 64) {
        float l0 = lsum[(size_t)b*NPIX + n0 + t];
        float l1 = lsum[(size_t)(BATCH + b)*NPIX + n0 + t];
        float inv = 1.f / (l0 + l1);
        w0s[t] = l0 * inv; w1s[t] = l1 * inv;
    }
    __syncthreads();
    {
        int cl = t >> 2, nc = (t & 3) * 16;
        size_t base = ((size_t)b*CCH + c0 + cl)*NPIX + n0 + nc;
        #pragma unroll
        for (int h = 0; h < 2; ++h) {
            bf16x8 a0 = *(const bf16x8*)(p0 + base + h*8);
            bf16x8 a1 = *(const bf16x8*)(p1 + base + h*8);
            #pragma unroll
            for (int j = 0; j < 8; ++j)
                tile[cl][nc + h*8 + j] = (float)a0[j]*w0s[nc + h*8 + j]
                                       + (float)a1[j]*w1s[nc + h*8 + j];
        }
    }
    __syncthreads();
    {
        int nr = t >> 2, cp = (t & 3) * 16;
        bf16x8 o0, o1;
        #pragma unroll
        for (int j = 0; j < 8; ++j) {
            o0[j] = (bf16)tile[cp + j    ][nr];
            o1[j] = (bf16)tile[cp + 8 + j][nr];
        }
        bf16* dst = h2t + ((size_t)b*NPIX + n0 + nr)*CCH + c0 + cp;
        *(bf16x8*)dst       = o0;
        *((bf16x8*)dst + 1) = o1;
    }
}

extern "C" void kernel_launch(void* const* d_in, const int* in_sizes, int n_in,
                              void* d_out, int out_size, void* d_ws, size_t ws_size,
                              hipStream_t stream) {
    (void)in_sizes; (void)n_in; (void)out_size; (void)ws_size;
    const float* x   = (const float*)d_in[0];
    const float* gnw = (const float*)d_in[1];
    const float* gnb = (const float*)d_in[2];
    const float* wq  = (const float*)d_in[3];
    const float* bq  = (const float*)d_in[4];
    const float* wk  = (const float*)d_in[5];
    const float* bk  = (const float*)d_in[6];
    const float* wv  = (const float*)d_in[7];
    const float* bv  = (const float*)d_in[8];
    const float* wp  = (const float*)d_in[9];
    const float* bp  = (const float*)d_in[10];
    const float cscale = 0.04419417382415922f;        // 512^-0.5

    char* ws = (char*)d_ws;
    bf16* wcat = (bf16*)ws;                           // [wq|wk|wv|wp] bf16, contiguous
    bf16* wpb  = wcat + 3*262144;
    float2* partials = (float2*)(ws + 4*524288);      // 1024 float2 = 8KB
    const size_t TEN = (size_t)BATCH*NPIX*CCH;
    bf16* hnt = (bf16*)(ws + 4*524288 + 16384);
    bf16* qt  = hnt + TEN;
    bf16* kt  = qt  + TEN;
    bf16* vch = kt  + TEN;
    bf16* pacc1 = vch + TEN;
    float* lsum = (float*)(pacc1 + TEN);
    bf16* pacc0 = hnt;                                // aliases hnt (dead after QKV gemm)
    bf16* h2t   = qt;                                 // aliases qt  (dead after attn)

    cvt_all<<<1024, 256, 0, stream>>>(wq, wk, wv, wp, wcat, cscale);

    gn_part<<<1024, 256, 0, stream>>>(x, partials);
    gn_norm_t<<<dim3(NPIX/64, CCH/64, BATCH), 256, 0, stream>>>(x, partials, gnw, gnb, hnt);

    gemm_qkv<<<dim3(NPIX/128, 12, BATCH), 256, 0, stream>>>(
        wcat, hnt, bq, bk, bv, qt, kt, vch, cscale);

    attn_flash<<<dim3(32, BATCH, 2), 512, 0, stream>>>(qt, kt, vch, pacc0, pacc1, lsum);

    merge_t<<<dim3(NPIX/64, CCH/64, BATCH), 256, 0, stream>>>(pacc0, pacc1, lsum, h2t);

    gemm_proj<<<dim3(NPIX/128, CCH/128, BATCH), 256, 0, stream>>>(
        wpb, h2t, bp, (float*)d_out, x);
}

// Round 13
// 279.954 us; speedup vs baseline: 1.0827x; 1.0827x over previous
//
#include <hip/hip_runtime.h>

#define NPIX 4096
#define CCH  512
#define NGRP 32
#define BATCH 4
#define NT   64

using bf16 = __bf16;
typedef __bf16 bf16x8 __attribute__((ext_vector_type(8)));
typedef __bf16 bf16x4 __attribute__((ext_vector_type(4)));
typedef float  f32x4  __attribute__((ext_vector_type(4)));

__device__ __forceinline__ f32x4 mfma16(bf16x8 a, bf16x8 b, f32x4 c) {
    return __builtin_amdgcn_mfma_f32_16x16x32_bf16(a, b, c, 0, 0, 0);
}

// async global->LDS DMA, 16B per lane. LDS dst = wave-uniform base + lane*16.
__device__ __forceinline__ void gld_lds16(const void* g, void* l) {
    __builtin_amdgcn_global_load_lds(
        (const __attribute__((address_space(1))) unsigned int*)g,
        (__attribute__((address_space(3))) unsigned int*)l,
        16, 0, 0);
}

// ---- swizzle helpers for [16-row][32-col] bf16 units (64B rows, 128B 2-row pairs)
__device__ __forceinline__ void swz_src(int l, int& drow, int& dcol) {
    int m = (l & 7) ^ (l >> 3);
    drow = 2 * (l >> 3) + (m >> 2);
    dcol = (m & 3) * 8;
}
// element offset where global (row c in 0..15, 16B-group g in 0..3) landed
__device__ __forceinline__ int swz_roff(int c, int g) {
    return ((c >> 1) << 6) + ((((((c & 1) << 2) | g)) ^ ((c >> 1) & 7)) << 3);
}

// ---------------- all weights fp32 -> bf16, one launch --------------------------
__global__ __launch_bounds__(256) void cvt_all(const float* __restrict__ wq,
                                               const float* __restrict__ wk,
                                               const float* __restrict__ wv,
                                               const float* __restrict__ wp,
                                               bf16* __restrict__ d, float cscale) {
    int i = blockIdx.x * 256 + threadIdx.x;           // float4 index, 0..262143
    int seg = i >> 16;                                // 65536 float4 per weight
    const float* s = (seg == 0) ? wq : (seg == 1) ? wk : (seg == 2) ? wv : wp;
    float scale = (seg == 0) ? cscale : 1.f;
    float4 v = ((const float4*)s)[i & 65535];
    bf16x4 o;
    o[0] = (bf16)(v.x*scale); o[1] = (bf16)(v.y*scale);
    o[2] = (bf16)(v.z*scale); o[3] = (bf16)(v.w*scale);
    ((bf16x4*)d)[i] = o;
}

// ---------------- groupnorm partial stats: 8 chunks per (b,g), 1024 blocks ------
__global__ __launch_bounds__(256) void gn_part(const float* __restrict__ x,
                                               float2* __restrict__ partials) {
    int blk = blockIdx.x;                             // bg = blk>>3, chunk = blk&7
    const float4* p = (const float4*)(x + (size_t)(blk >> 3) * 65536 + (blk & 7) * 8192);
    float s = 0.f, ss = 0.f;
    int t = threadIdx.x;
    #pragma unroll
    for (int i = 0; i < 8; ++i) {
        float4 v = p[t + i*256];
        s  += v.x + v.y + v.z + v.w;
        ss += v.x*v.x + v.y*v.y + v.z*v.z + v.w*v.w;
    }
    __shared__ float r1[256], r2[256];
    r1[t] = s; r2[t] = ss;
    __syncthreads();
    for (int st = 128; st > 0; st >>= 1) {
        if (t < st) { r1[t] += r1[t+st]; r2[t] += r2[t+st]; }
        __syncthreads();
    }
    if (t == 0) partials[blk] = make_float2(r1[0], r2[0]);
}

// ---------------- groupnorm apply + transpose -> hn_t[b][n][c] bf16 ----------------
// finalizes stats inline from the 8 partials per group (fixed order, deterministic)
__global__ __launch_bounds__(256) void gn_norm_t(const float* __restrict__ x,
                                                 const float2* __restrict__ partials,
                                                 const float* __restrict__ gw,
                                                 const float* __restrict__ gb,
                                                 bf16* __restrict__ hnt) {
    __shared__ float tile[64][65];
    int n0 = blockIdx.x * 64, c0 = blockIdx.y * 64, b = blockIdx.z;
    int t = threadIdx.x;
    {
        int cr = t >> 4;
        int nc = (t & 15) * 4;
        #pragma unroll
        for (int rep = 0; rep < 4; ++rep) {
            int c = c0 + rep*16 + cr;
            int grp = b*NGRP + (c >> 4);
            float s = 0.f, ss = 0.f;
            #pragma unroll
            for (int k = 0; k < 8; ++k) {
                float2 pp = partials[grp*8 + k];
                s += pp.x; ss += pp.y;
            }
            float mu   = s * (1.f/65536.f);
            float rsig = rsqrtf(ss * (1.f/65536.f) - mu*mu + 1e-6f);
            float w = gw[c], bb = gb[c];
            float4 v = *(const float4*)(x + ((size_t)b*CCH + c)*NPIX + n0 + nc);
            float* dst = &tile[rep*16 + cr][nc];
            dst[0] = (v.x - mu)*rsig*w + bb;
            dst[1] = (v.y - mu)*rsig*w + bb;
            dst[2] = (v.z - mu)*rsig*w + bb;
            dst[3] = (v.w - mu)*rsig*w + bb;
        }
    }
    __syncthreads();
    {
        int nr = t >> 2;
        int cp = (t & 3) * 16;
        bf16x8 o0, o1;
        #pragma unroll
        for (int j = 0; j < 8; ++j) {
            o0[j] = (bf16)tile[cp + j    ][nr];
            o1[j] = (bf16)tile[cp + 8 + j][nr];
        }
        bf16* dst = hnt + ((size_t)b*NPIX + n0 + nr)*CCH + c0 + cp;
        *(bf16x8*)dst       = o0;
        *((bf16x8*)dst + 1) = o1;
    }
}

// ---------------- fused QKV GEMM: one launch over concat [1536x512] weights --------
__global__ __launch_bounds__(256, 2)
void gemm_qkv(const bf16* __restrict__ Wcat, const bf16* __restrict__ X,
              const float* __restrict__ bq, const float* __restrict__ bk,
              const float* __restrict__ bv, bf16* __restrict__ qt,
              bf16* __restrict__ kt, bf16* __restrict__ vch, float cscale) {
    __shared__ bf16 tX[2][4096];   // [128][32] swizzled
    __shared__ bf16 tW[2][4096];
    int n0 = blockIdx.x * 128, o0g = blockIdx.y * 128, b = blockIdx.z;
    int seg = o0g >> 9, osel = o0g & 511;
    const float* bias = (seg == 0) ? bq : (seg == 1) ? bk : bv;
    bf16* Yb = (seg == 0) ? qt : (seg == 1) ? kt : vch;
    float osc = (seg == 0) ? cscale : 1.f;
    bool vmode = (seg == 2);

    int t = threadIdx.x, lane = t & 63, w = t >> 6;
    int wm = (w >> 1) * 64, wn = (w & 1) * 64;
    int col = lane & 15, g = lane >> 4;
    int roff = swz_roff(col, g);
    int drow, dcol;
    swz_src(lane, drow, dcol);
    f32x4 acc[4][4] = {};
    const bf16* gX = X + ((size_t)b*NPIX + n0) * CCH;
    const bf16* gW = Wcat + (size_t)o0g * CCH;

    auto stage = [&](int buf, int k0) {
        #pragma unroll
        for (int i = 0; i < 2; ++i) {
            int rb = (w*2 + i) * 16;
            gld_lds16(gX + (size_t)(rb + drow)*CCH + k0 + dcol, &tX[buf][rb*32]);
            gld_lds16(gW + (size_t)(rb + drow)*CCH + k0 + dcol, &tW[buf][rb*32]);
        }
    };

    stage(0, 0);
    __syncthreads();

    for (int it = 0; it < 16; ++it) {
        int buf = it & 1;
        if (it < 15) stage(buf ^ 1, (it + 1) * 32);
        bf16x8 fA[4], fB[4];
        #pragma unroll
        for (int i = 0; i < 4; ++i) {
            if (!vmode) {
                fA[i] = *(bf16x8*)&tX[buf][(wm + i*16)*32 + roff];
                fB[i] = *(bf16x8*)&tW[buf][(wn + i*16)*32 + roff];
            } else {
                fA[i] = *(bf16x8*)&tW[buf][(wm + i*16)*32 + roff];
                fB[i] = *(bf16x8*)&tX[buf][(wn + i*16)*32 + roff];
            }
        }
        #pragma unroll
        for (int i = 0; i < 4; ++i)
            #pragma unroll
            for (int j = 0; j < 4; ++j)
                acc[i][j] = mfma16(fA[i], fB[j], acc[i][j]);
        __syncthreads();
    }

    int row4 = g * 4;
    #pragma unroll
    for (int i = 0; i < 4; ++i) {
        #pragma unroll
        for (int j = 0; j < 4; ++j) {
            #pragma unroll
            for (int r = 0; r < 4; ++r) {
                float vv = acc[i][j][r];
                int m = wm + i*16 + row4 + r;
                int n = wn + j*16 + col;
                if (!vmode) {
                    int sp = n0 + m, o = osel + n;
                    Yb[((size_t)b*NPIX + sp)*CCH + o] = (bf16)(vv + osc*bias[o]);
                } else {
                    int o = osel + m, sp = n0 + n;
                    Yb[((size_t)b*CCH + o)*NPIX + sp] = (bf16)(vv + bias[o]);
                }
            }
        }
    }
}

// ---------------- proj GEMM: D[o][i] fp32 + bias + residual ------------------------
__global__ __launch_bounds__(256, 2)
void gemm_proj(const bf16* __restrict__ W, const bf16* __restrict__ X,
               const float* __restrict__ bias, float* __restrict__ Yf,
               const float* __restrict__ resid) {
    __shared__ bf16 tX[2][4096];
    __shared__ bf16 tW[2][4096];
    int n0 = blockIdx.x * 128, o0 = blockIdx.y * 128, b = blockIdx.z;
    int t = threadIdx.x, lane = t & 63, w = t >> 6;
    int wm = (w >> 1) * 64, wn = (w & 1) * 64;
    int col = lane & 15, g = lane >> 4;
    int roff = swz_roff(col, g);
    int drow, dcol;
    swz_src(lane, drow, dcol);
    f32x4 acc[4][4] = {};
    const bf16* gX = X + ((size_t)b*NPIX + n0) * CCH;
    const bf16* gW = W + (size_t)o0 * CCH;

    auto stage = [&](int buf, int k0) {
        #pragma unroll
        for (int i = 0; i < 2; ++i) {
            int rb = (w*2 + i) * 16;
            gld_lds16(gX + (size_t)(rb + drow)*CCH + k0 + dcol, &tX[buf][rb*32]);
            gld_lds16(gW + (size_t)(rb + drow)*CCH + k0 + dcol, &tW[buf][rb*32]);
        }
    };

    stage(0, 0);
    __syncthreads();

    for (int it = 0; it < 16; ++it) {
        int buf = it & 1;
        if (it < 15) stage(buf ^ 1, (it + 1) * 32);
        bf16x8 fA[4], fB[4];
        #pragma unroll
        for (int i = 0; i < 4; ++i) {
            fA[i] = *(bf16x8*)&tW[buf][(wm + i*16)*32 + roff];
            fB[i] = *(bf16x8*)&tX[buf][(wn + i*16)*32 + roff];
        }
        #pragma unroll
        for (int i = 0; i < 4; ++i)
            #pragma unroll
            for (int j = 0; j < 4; ++j)
                acc[i][j] = mfma16(fA[i], fB[j], acc[i][j]);
        __syncthreads();
    }

    int row4 = g * 4;
    #pragma unroll
    for (int i = 0; i < 4; ++i) {
        #pragma unroll
        for (int j = 0; j < 4; ++j) {
            #pragma unroll
            for (int r = 0; r < 4; ++r) {
                int o = o0 + wm + i*16 + row4 + r;
                int sp = n0 + wn + j*16 + col;
                size_t idx = ((size_t)b*CCH + o)*NPIX + sp;
                Yf[idx] = acc[i][j][r] + bias[o] + resid[idx];
            }
        }
    }
}

// ---------------- flash attention v8 (R11, best measured): PV(t-1) ∥ QK^T(t) -------
// Body t: load V-frags(t-1) -> regs; lgkmcnt+sched_barrier; issue stage(t+1) DMA;
// PV(t-1) (Pl[prev] + reg V) and QK^T(t) (Kt[cur]) interleave; exp -> Pl[cur];
// one __syncthreads per body.
__global__ __launch_bounds__(512, 2)
void attn_flash(const bf16* __restrict__ qt, const bf16* __restrict__ kt,
                const bf16* __restrict__ v, bf16* __restrict__ pacc0,
                bf16* __restrict__ pacc1, float* __restrict__ lsum) {
    __shared__ bf16 Kt[2][16384];      // [32 j][512 c], 16B-group XOR swizzle
    __shared__ bf16 Vt[2][16384];      // [512 c][32 j], 16x32-unit swizzle
    __shared__ bf16 Pl[2][8][16][40];  // double-buffered per-wave P tiles
    __shared__ float Ls[128];          // 1/rowsum for all 128 q-rows

    const int L  = blockIdx.x + 32 * blockIdx.y + 128 * blockIdx.z;
    const int gx = L & 7, ix = L >> 3;
    const int b  = gx & 3, jz = gx >> 2;

    const int t = threadIdx.x, lane = t & 63, w = t >> 6;
    const int q0 = ix * 128 + w * 16;          // q-rows owned for QK^T/softmax
    const int col = lane & 15, g = lane >> 4, kq = g * 8;
    const int jbase = jz * 2048;

    const bf16* kbase = kt + (size_t)b*NPIX*CCH;
    const bf16* vbase = v  + (size_t)b*CCH*NPIX;
    int drow, dcol; swz_src(lane, drow, dcol);
    const int kx0 = (col & 7) << 4;
    const int vro = 2*swz_roff(col, g);

    bf16x8 qf[16];
    {
        const bf16* qrow = qt + ((size_t)b*NPIX + q0 + col)*CCH + kq;
        #pragma unroll
        for (int kk = 0; kk < 16; ++kk) qf[kk] = *(const bf16x8*)(qrow + kk*32);
    }

    auto stage = [&](int buf, int j0) {
        #pragma unroll
        for (int i = 0; i < 4; ++i) {
            int row = w*4 + i;
            gld_lds16((const char*)(kbase + (size_t)(j0 + row)*CCH) + ((lane*16) ^ ((row & 7) << 4)),
                      (char*)&Kt[buf][0] + row*1024);
        }
        #pragma unroll
        for (int i = 0; i < 4; ++i) {
            int blk = w*4 + i;
            gld_lds16(vbase + (size_t)(blk*16 + drow)*NPIX + j0 + dcol,
                      (char*)&Vt[buf][0] + blk*1024);
        }
    };

    f32x4 acc[8][4] = {};                      // [q-tile][c-tile]; channels w*64..+63
    float lacc[4] = {0.f, 0.f, 0.f, 0.f};

    auto qkt_exp = [&](int buf) {
        f32x4 s0a = {}, s0b = {}, s1a = {}, s1b = {};
        const char* kb0 = (const char*)&Kt[buf][0] + col*1024;
        const char* kb1 = kb0 + 16*1024;
        #pragma unroll
        for (int kk = 0; kk < 16; kk += 2) {
            int e0 = (kk*64     + g*16) ^ kx0;
            int e1 = ((kk+1)*64 + g*16) ^ kx0;
            s0a = mfma16(qf[kk],   *(const bf16x8*)(kb0 + e0), s0a);
            s1a = mfma16(qf[kk],   *(const bf16x8*)(kb1 + e0), s1a);
            s0b = mfma16(qf[kk+1], *(const bf16x8*)(kb0 + e1), s0b);
            s1b = mfma16(qf[kk+1], *(const bf16x8*)(kb1 + e1), s1b);
        }
        f32x4 s0 = s0a + s0b;
        f32x4 s1 = s1a + s1b;
        #pragma unroll
        for (int r = 0; r < 4; ++r) {
            float p0 = __expf(s0[r]);
            float p1 = __expf(s1[r]);
            lacc[r] += p0 + p1;
            Pl[buf][w][g*4 + r][col]      = (bf16)p0;
            Pl[buf][w][g*4 + r][col + 16] = (bf16)p1;
        }
    };

    stage(0, jbase);
    __syncthreads();

    // peeled body 0: no PV yet
    stage(1, jbase + 32);
    qkt_exp(0);
    __syncthreads();

    for (int it = 1; it < NT; ++it) {
        const int buf = it & 1, pb = buf ^ 1;

        // early V-frag loads for PV(it-1) -- must complete before the stage DMA
        // overwrites Vt[pb] (wave-private blocks; in-wave order pinned below)
        const char* vb = (const char*)&Vt[pb][0] + (w << 12);
        bf16x8 bv0 = *(const bf16x8*)(vb          + vro);
        bf16x8 bv1 = *(const bf16x8*)(vb + 1024   + vro);
        bf16x8 bv2 = *(const bf16x8*)(vb + 2048   + vro);
        bf16x8 bv3 = *(const bf16x8*)(vb + 3072   + vro);
        asm volatile("s_waitcnt lgkmcnt(0)" ::: "memory");
        __builtin_amdgcn_sched_barrier(0);

        if (it < NT-1) stage(pb, jbase + (it + 1) * 32);

        // PV(it-1): independent of QK^T(it) below -> scheduler interleaves
        #pragma unroll
        for (int qtl = 0; qtl < 8; ++qtl) {
            bf16x8 pa = *(bf16x8*)&Pl[pb][qtl][col][kq];
            acc[qtl][0] = mfma16(pa, bv0, acc[qtl][0]);
            acc[qtl][1] = mfma16(pa, bv1, acc[qtl][1]);
            acc[qtl][2] = mfma16(pa, bv2, acc[qtl][2]);
            acc[qtl][3] = mfma16(pa, bv3, acc[qtl][3]);
        }

        qkt_exp(buf);
        __syncthreads();
    }

    // tail: PV(NT-1), buffers parity 1
    {
        const char* vb = (const char*)&Vt[1][0] + (w << 12);
        bf16x8 bv0 = *(const bf16x8*)(vb          + vro);
        bf16x8 bv1 = *(const bf16x8*)(vb + 1024   + vro);
        bf16x8 bv2 = *(const bf16x8*)(vb + 2048   + vro);
        bf16x8 bv3 = *(const bf16x8*)(vb + 3072   + vro);
        #pragma unroll
        for (int qtl = 0; qtl < 8; ++qtl) {
            bf16x8 pa = *(bf16x8*)&Pl[1][qtl][col][kq];
            acc[qtl][0] = mfma16(pa, bv0, acc[qtl][0]);
            acc[qtl][1] = mfma16(pa, bv1, acc[qtl][1]);
            acc[qtl][2] = mfma16(pa, bv2, acc[qtl][2]);
            acc[qtl][3] = mfma16(pa, bv3, acc[qtl][3]);
        }
    }

    // row sums for own 16 q-rows -> Ls + global lsum
    #pragma unroll
    for (int r = 0; r < 4; ++r) {
        float s = lacc[r];
        #pragma unroll
        for (int off = 1; off < 16; off <<= 1) s += __shfl_xor(s, off);
        if (col == 0) {
            Ls[w*16 + g*4 + r] = 1.f / s;
            lsum[((size_t)jz*BATCH + b)*NPIX + q0 + g*4 + r] = s;
        }
    }
    __syncthreads();

    // write partials: channels [w*64, w*64+64), all 128 q-rows
    bf16* pout = jz ? pacc1 : pacc0;
    const int q0b = ix * 128;
    #pragma unroll
    for (int qtl = 0; qtl < 8; ++qtl) {
        f32x4 rlq = *(const f32x4*)&Ls[qtl*16 + g*4];
        #pragma unroll
        for (int i = 0; i < 4; ++i) {
            int ch = w*64 + i*16 + col;
            bf16x4 ov;
            #pragma unroll
            for (int r = 0; r < 4; ++r) ov[r] = (bf16)(acc[qtl][i][r] * rlq[r]);
            *(bf16x4*)(pout + ((size_t)b*CCH + ch)*NPIX + q0b + qtl*16 + g*4) = ov;
        }
    }
}

// ---------------- merge j-split partials + transpose -> h2t[b][n][c] bf16 -----------
__global__ __launch_bounds__(256)
void merge_t(const bf16* __restrict__ p0, const bf16* __restrict__ p1,
             const float* __restrict__ lsum, bf16* __restrict__ h2t) {
    __shared__ float tile[64][65];
    __shared__ float w0s[64], w1s[64];
    int n0 = blockIdx.x * 64, c0 = blockIdx.y * 64, b = blockIdx.z;
    int t = threadIdx.x;
    if (t < 64) {
        float l0 = lsum[(size_t)b*NPIX + n0 + t];
        float l1 = lsum[(size_t)(BATCH + b)*NPIX + n0 + t];
        float inv = 1.f / (l0 + l1);
        w0s[t] = l0 * inv; w1s[t] = l1 * inv;
    }
    __syncthreads();
    {
        int cl = t >> 2, nc = (t & 3) * 16;
        size_t base = ((size_t)b*CCH + c0 + cl)*NPIX + n0 + nc;
        #pragma unroll
        for (int h = 0; h < 2; ++h) {
            bf16x8 a0 = *(const bf16x8*)(p0 + base + h*8);
            bf16x8 a1 = *(const bf16x8*)(p1 + base + h*8);
            #pragma unroll
            for (int j = 0; j < 8; ++j)
                tile[cl][nc + h*8 + j] = (float)a0[j]*w0s[nc + h*8 + j]
                                       + (float)a1[j]*w1s[nc + h*8 + j];
        }
    }
    __syncthreads();
    {
        int nr = t >> 2, cp = (t & 3) * 16;
        bf16x8 o0, o1;
        #pragma unroll
        for (int j = 0; j < 8; ++j) {
            o0[j] = (bf16)tile[cp + j    ][nr];
            o1[j] = (bf16)tile[cp + 8 + j][nr];
        }
        bf16* dst = h2t + ((size_t)b*NPIX + n0 + nr)*CCH + c0 + cp;
        *(bf16x8*)dst       = o0;
        *((bf16x8*)dst + 1) = o1;
    }
}

extern "C" void kernel_launch(void* const* d_in, const int* in_sizes, int n_in,
                              void* d_out, int out_size, void* d_ws, size_t ws_size,
                              hipStream_t stream) {
    (void)in_sizes; (void)n_in; (void)out_size; (void)ws_size;
    const float* x   = (const float*)d_in[0];
    const float* gnw = (const float*)d_in[1];
    const float* gnb = (const float*)d_in[2];
    const float* wq  = (const float*)d_in[3];
    const float* bq  = (const float*)d_in[4];
    const float* wk  = (const float*)d_in[5];
    const float* bk  = (const float*)d_in[6];
    const float* wv  = (const float*)d_in[7];
    const float* bv  = (const float*)d_in[8];
    const float* wp  = (const float*)d_in[9];
    const float* bp  = (const float*)d_in[10];
    const float cscale = 0.04419417382415922f;        // 512^-0.5

    char* ws = (char*)d_ws;
    bf16* wcat = (bf16*)ws;                           // [wq|wk|wv|wp] bf16, contiguous
    bf16* wpb  = wcat + 3*262144;
    float2* partials = (float2*)(ws + 4*524288);      // 1024 float2 = 8KB
    const size_t TEN = (size_t)BATCH*NPIX*CCH;
    bf16* hnt = (bf16*)(ws + 4*524288 + 16384);
    bf16* qt  = hnt + TEN;
    bf16* kt  = qt  + TEN;
    bf16* vch = kt  + TEN;
    bf16* pacc1 = vch + TEN;
    float* lsum = (float*)(pacc1 + TEN);
    bf16* pacc0 = hnt;                                // aliases hnt (dead after QKV gemm)
    bf16* h2t   = qt;                                 // aliases qt  (dead after attn)

    cvt_all<<<1024, 256, 0, stream>>>(wq, wk, wv, wp, wcat, cscale);

    gn_part<<<1024, 256, 0, stream>>>(x, partials);
    gn_norm_t<<<dim3(NPIX/64, CCH/64, BATCH), 256, 0, stream>>>(x, partials, gnw, gnb, hnt);

    gemm_qkv<<<dim3(NPIX/128, 12, BATCH), 256, 0, stream>>>(
        wcat, hnt, bq, bk, bv, qt, kt, vch, cscale);

    attn_flash<<<dim3(32, BATCH, 2), 512, 0, stream>>>(qt, kt, vch, pacc0, pacc1, lsum);

    merge_t<<<dim3(NPIX/64, CCH/64, BATCH), 256, 0, stream>>>(pacc0, pacc1, lsum, h2t);

    gemm_proj<<<dim3(NPIX/128, CCH/128, BATCH), 256, 0, stream>>>(
        wpb, h2t, bp, (float*)d_out, x);
}